// Round 5
// baseline (447.958 us; speedup 1.0000x reference)
//
#include <hip/hip_runtime.h>
#include <math.h>

#define DIM   256
#define NUM_E 1024
#define HWN   1024          // 32*32 spatial per batch
#define NROW  32768         // 32*1024 flattened rows
#define NELEM 8388608       // 32*256*32*32

#define BM 128
#define BN 128
#define BK 32
#define NCH 8               // NUM_E / BN candidate chunks

// ---------------------------------------------------------------------------
// One 128-element half of numpy's pairwise sum-of-squares: 8 accumulators
// r[j] += fl(a[i+j]^2), combined ((r0+r1)+(r2+r3))+((r4+r5)+(r6+r7)).
// Square and add round separately -> contraction off.
__device__ __forceinline__ float np_sumsq_128(const float* __restrict__ a,
                                              int stride) {
#pragma clang fp contract(off)
    float r[8];
#pragma unroll
    for (int j = 0; j < 8; ++j) { const float v = a[j * stride]; r[j] = v * v; }
    for (int i = 8; i < 128; i += 8) {
#pragma unroll
        for (int j = 0; j < 8; ++j) {
            const float v = a[(i + j) * stride];
            r[j] += v * v;
        }
    }
    return ((r[0] + r[1]) + (r[2] + r[3])) + ((r[4] + r[5]) + (r[6] + r[7]));
}

// merged ||z_r||^2 (blocks 0..255) and ||e_k||^2 (blocks 256..263);
// 2 threads per row (independent pairwise halves), shuffle-combined h0+h1
// exactly as numpy's final add -> bit-exact.
__global__ __launch_bounds__(256) void k_pre(const float* __restrict__ z,
                                             const float* __restrict__ emb,
                                             float* __restrict__ zz,
                                             float* __restrict__ ee) {
    const int g = blockIdx.x * 256 + threadIdx.x;
    if (blockIdx.x < 256) {                     // zz part: g in [0, 65536)
        const int r = g >> 1, hh = g & 1;
        const int b = r >> 10, hw = r & (HWN - 1);
        const float h = np_sumsq_128(
            z + (size_t)b * DIM * HWN + (size_t)(hh * 128) * HWN + hw, HWN);
        const float o = __shfl_down(h, 1, 64);
        if (!hh) zz[r] = h + o;                 // fl(h0 + h1)
    } else {                                    // ee part: ge in [0, 2048)
        const int ge = g - 65536;
        const int k = ge >> 1, hh = ge & 1;
        const float h = np_sumsq_128(emb + (size_t)k * DIM + hh * 128, 1);
        const float o = __shfl_down(h, 1, 64);
        if (!hh) ee[k] = h + o;
    }
}

// ---------------------------------------------------------------------------
// GEMM-tiled bit-exact distance + per-chunk argmin candidates.
// BM=128 x BN=128 x BK=32, 256 threads, 8x8 microtile; dot = sequential fmaf
// chain over d ascending; dist = fl(fl(zz+ee) - fl(2*dot)); strict-< argmin.
//
// es LDS layout: es4[k*32 + (c ^ ((k>>2)&7))], c = column-group (4 cols).
// Writes: thread (kg,ng) -> slot ng^kg: every bank-group 2x per quarter-wave.
// Reads: thread tx reads c = tx and c = tx+16 -> slots (tx^k4), (tx^k4)+16:
// bank-group (tx&7)^k4 covered exactly 2x per quarter-wave.  All LDS <= 2-way
// (free per m136).  zs reads are quarter-wave broadcasts (same address).
__global__ __launch_bounds__(256, 4) void k_gemm(
        const float* __restrict__ z, const float* __restrict__ emb,
        const float* __restrict__ zzg, const float* __restrict__ eeg,
        float* __restrict__ cv, int* __restrict__ ci) {
    __shared__ __align__(16) float zs[BK * BM];   // zs[k][m], row stride 128
    __shared__ __align__(16) float es[BK * BN];   // es[k][slot], swizzled
    float4* zs4 = (float4*)zs;
    float4* es4 = (float4*)es;

    const int tid = threadIdx.x;
    const int nb  = blockIdx.x & (NCH - 1);
    const int mb  = blockIdx.x >> 3;
    const int R0  = mb * BM;
    const int b   = R0 >> 10;
    const int hw0 = R0 & (HWN - 1);

    const int tx = tid & 15, ty = tid >> 4;
    const int kg = tid & 7, ng = tid >> 3;       // es staging ownership
    const int wslot = ng ^ kg;                   // conflict-free write slot
    const int m4 = tid & 31, kzb = tid >> 5;     // zs staging ownership

    const float* zbase = z + (size_t)b * DIM * HWN + hw0;
    const float4* embq = (const float4*)(emb + ((size_t)nb * BN + ng * 4) * DIM);

    float acc[8][8];
#pragma unroll
    for (int i = 0; i < 8; ++i)
#pragma unroll
        for (int j = 0; j < 8; ++j) acc[i][j] = 0.f;

    for (int k0 = 0; k0 < DIM; k0 += BK) {
        __syncthreads();
        // stage zs[k][m] = z[b][k0+k][hw0+m] (k-major already; coalesced)
#pragma unroll
        for (int q = 0; q < 4; ++q) {
            const int k = q * 8 + kzb;
            zs4[k * 32 + m4] =
                *(const float4*)(zbase + (size_t)(k0 + k) * HWN + m4 * 4);
        }
        // stage es rows kg*4..kg*4+3, column-group ng, via register transpose
        {
            const float4 g0 = embq[0 * 64 + (k0 >> 2) + kg];
            const float4 g1 = embq[1 * 64 + (k0 >> 2) + kg];
            const float4 g2 = embq[2 * 64 + (k0 >> 2) + kg];
            const float4 g3 = embq[3 * 64 + (k0 >> 2) + kg];
            es4[(kg * 4 + 0) * 32 + wslot] = make_float4(g0.x, g1.x, g2.x, g3.x);
            es4[(kg * 4 + 1) * 32 + wslot] = make_float4(g0.y, g1.y, g2.y, g3.y);
            es4[(kg * 4 + 2) * 32 + wslot] = make_float4(g0.z, g1.z, g2.z, g3.z);
            es4[(kg * 4 + 3) * 32 + wslot] = make_float4(g0.w, g1.w, g2.w, g3.w);
        }
        __syncthreads();

#pragma unroll
        for (int k4 = 0; k4 < 8; ++k4) {
            const int sA = tx ^ k4;              // column-group tx
            const int sB = sA + 16;              // column-group tx+16
#pragma unroll
            for (int kj = 0; kj < 4; ++kj) {
                const int k = k4 * 4 + kj;
                const float4 za0 = zs4[k * 32 + ty * 2];
                const float4 za1 = zs4[k * 32 + ty * 2 + 1];
                const float4 eb0 = es4[k * 32 + sA];
                const float4 eb1 = es4[k * 32 + sB];
                const float zf[8] = {za0.x, za0.y, za0.z, za0.w,
                                     za1.x, za1.y, za1.z, za1.w};
                const float ef[8] = {eb0.x, eb0.y, eb0.z, eb0.w,
                                     eb1.x, eb1.y, eb1.z, eb1.w};
#pragma unroll
                for (int i = 0; i < 8; ++i)
#pragma unroll
                    for (int j = 0; j < 8; ++j)
                        acc[i][j] = fmaf(zf[i], ef[j], acc[i][j]);
            }
        }
    }

    // epilogue: dist + per-row argmin over this block's 128 cols
    const int n0a = nb * BN + tx * 4;        // cols for j = 0..3
    const int n0b = n0a + 64;                // cols for j = 4..7
#pragma unroll
    for (int i = 0; i < 8; ++i) {
        const int r = R0 + ty * 8 + i;
        const float zzv = zzg[r];
        float bv = 1e30f; int bi = 0;
#pragma unroll
        for (int j = 0; j < 8; ++j) {
            const int kk = (j < 4) ? (n0a + j) : (n0b + j - 4);
            const float t    = zzv + eeg[kk];
            const float dist = t - 2.0f * acc[i][j];
            if (dist < bv) { bv = dist; bi = kk; }
        }
#pragma unroll
        for (int off = 1; off <= 8; off <<= 1) {
            const float v2 = __shfl_xor(bv, off, 64);
            const int   i2 = __shfl_xor(bi, off, 64);
            if (v2 < bv || (v2 == bv && i2 < bi)) { bv = v2; bi = i2; }
        }
        if (tx == 0) {
            cv[(size_t)nb * NROW + r] = bv;
            ci[(size_t)nb * NROW + r] = bi;
        }
    }
}

// final candidate reduce: 8 chunks (ascending k) per row -> idx
__global__ __launch_bounds__(256) void k_amfin(const float* __restrict__ cv,
                                               const int* __restrict__ ci,
                                               float* __restrict__ oidx) {
    const int r = blockIdx.x * 256 + threadIdx.x;
    float bv = cv[r]; int bi = ci[r];
#pragma unroll
    for (int c = 1; c < NCH; ++c) {
        const float v = cv[(size_t)c * NROW + r];
        const int   x = ci[(size_t)c * NROW + r];
        if (v < bv || (v == bv && x < bi)) { bv = v; bi = x; }
    }
    oidx[r] = (float)bi;
}

// ---------------------------------------------------------------------------
// fused zero + scatter: writes every one-hot row directly (coalesced float4)
__global__ __launch_bounds__(256) void k_onehot(const float* __restrict__ idxf,
                                                float4* __restrict__ enc4) {
    const int t = threadIdx.x;
#pragma unroll
    for (int i = 0; i < 16; ++i) {
        const int row = blockIdx.x * 16 + i;
        const int k = (int)idxf[row];
        float4 v = make_float4(0.f, 0.f, 0.f, 0.f);
        if ((k >> 2) == t) ((float*)&v)[k & 3] = 1.0f;
        enc4[(size_t)row * 256 + t] = v;
    }
}

// z_q (straight-through, numpy op order) + per-block loss partial (no atomics)
__global__ __launch_bounds__(256) void k_zq(const float* __restrict__ z,
                                            const float* __restrict__ emb,
                                            const float* __restrict__ idxf,
                                            float* __restrict__ ozq,
                                            double* __restrict__ partials) {
    const int gid = blockIdx.x * 256 + threadIdx.x;   // NELEM/4 threads
    const int hw4 = gid & 255;
    const int d   = (gid >> 8) & 255;
    const int b   = gid >> 16;
    const size_t zoff = ((size_t)(b * DIM + d)) * HWN + hw4 * 4;
    const float4 zv = *(const float4*)(z + zoff);
    const int n0 = b * HWN + hw4 * 4;
    const int i0 = (int)idxf[n0 + 0], i1 = (int)idxf[n0 + 1];
    const int i2 = (int)idxf[n0 + 2], i3 = (int)idxf[n0 + 3];
    const float e0 = emb[i0 * DIM + d], e1 = emb[i1 * DIM + d];
    const float e2 = emb[i2 * DIM + d], e3 = emb[i3 * DIM + d];
    const float t0 = e0 - zv.x, t1 = e1 - zv.y, t2 = e2 - zv.z, t3 = e3 - zv.w;
    const float4 o = make_float4(zv.x + t0, zv.y + t1, zv.z + t2, zv.w + t3);
    *(float4*)(ozq + zoff) = o;
    double s = (double)t0 * t0 + (double)t1 * t1 + (double)t2 * t2 + (double)t3 * t3;
#pragma unroll
    for (int off = 32; off > 0; off >>= 1) s += __shfl_down(s, off, 64);
    __shared__ double pw[4];
    if ((threadIdx.x & 63) == 0) pw[threadIdx.x >> 6] = s;
    __syncthreads();
    if (threadIdx.x == 0)
        partials[blockIdx.x] = (pw[0] + pw[1]) + (pw[2] + pw[3]);
}

__global__ __launch_bounds__(256) void k_fin(const double* __restrict__ partials,
                                             float* __restrict__ out) {
    const int t = threadIdx.x;
    double s = 0.0;
    for (int i = t; i < 8192; i += 256) s += partials[i];
#pragma unroll
    for (int off = 32; off > 0; off >>= 1) s += __shfl_down(s, off, 64);
    __shared__ double w[4];
    if ((t & 63) == 0) w[t >> 6] = s;
    __syncthreads();
    if (t == 0) {
        const double tot = (w[0] + w[1]) + (w[2] + w[3]);
        const float m = (float)(tot / 8388608.0);   // /2^23 exact
        out[0] = m + 0.25f * m;
    }
}

// ---------------------------------------------------------------------------
extern "C" void kernel_launch(void* const* d_in, const int* in_sizes, int n_in,
                              void* d_out, int out_size, void* d_ws, size_t ws_size,
                              hipStream_t stream) {
    const float* z   = (const float*)d_in[0];
    const float* emb = (const float*)d_in[1];
    float* out   = (float*)d_out;
    float* o_zq  = out + 1;                              // 8,388,608
    float* o_enc = o_zq + NELEM;                         // 33,554,432
    float* o_idx = o_enc + (size_t)NROW * NUM_E;         // 32,768

    // all scratch inside o_enc; k_onehot overwrites it LAST
    float*  s_cv = o_enc;                                // 262,144
    int*    s_ci = (int*)(o_enc + 262144);               // 262,144
    float*  s_zz = o_enc + 524288;                       // 32,768
    float*  s_ee = o_enc + 557056;                       // 1,024
    double* s_ps = (double*)(((size_t)(o_enc + 600000) + 7) & ~(size_t)7); // 8,192

    k_pre   <<<264, 256, 0, stream>>>(z, emb, s_zz, s_ee);
    k_gemm  <<<(NROW / BM) * NCH, 256, 0, stream>>>(z, emb, s_zz, s_ee, s_cv, s_ci);
    k_amfin <<<NROW / 256, 256, 0, stream>>>(s_cv, s_ci, o_idx);
    k_zq    <<<NELEM / 4 / 256, 256, 0, stream>>>(z, emb, o_idx, o_zq, s_ps);
    k_fin   <<<1, 256, 0, stream>>>(s_ps, out);
    k_onehot<<<NROW / 16, 256, 0, stream>>>(o_idx, (float4*)o_enc);
}